// Round 4
// baseline (233.190 us; speedup 1.0000x reference)
//
#include <hip/hip_runtime.h>

// Problem constants (fixed by setup_inputs)
constexpr int B = 4, Q = 100, C = 40, Cp1 = 41, HW = 65536;

// Fused kernel: 512 blocks (4 b x 128 segments of 512 px), 256 threads (4 waves).
constexpr int FBLKS = 512;

// Workspace layout (4-byte words):
//  [0, 16000)        counts    u32 [B][Q][C]
//  [16000, 16160)    tsum      u32 [B][C]
//  [16160]           ce_sum    f32
//  [16161]           n_valid   u32
//  [16162, 32562)    inter_ext f32 [B*Q][41]   (col 40 = ignored-pixel sig sum)
constexpr int WS_WORDS = 32562;

typedef __attribute__((ext_vector_type(8))) short short8;   // 8 bf16
typedef __attribute__((ext_vector_type(4))) float f32x4;

__device__ __forceinline__ short f2bf(float f) {            // RNE f32->bf16
    unsigned u = __float_as_uint(f);
    u += 0x7FFF + ((u >> 16) & 1);
    return (short)(u >> 16);
}

__global__ void kZ(unsigned* __restrict__ ws, int n) {
    int i = blockIdx.x * blockDim.x + threadIdx.x;
    for (; i < n; i += gridDim.x * blockDim.x) ws[i] = 0u;
}

// R3: (1) launch_bounds(256,2) so the 2x16 float2 double-buffer lives in VGPRs
// (R2 got squeezed to 48 VGPRs -> pipeline collapsed to just-in-time loads);
// (2) next tile's loads issued BEFORE current tile's process+MFMA, raw barriers
// never drain vmcnt; (3) one-hot B prebuilt ONCE in LDS (depends only on
// targets) -> MFMA phase is 2 ds_read_b128 + mfma per kc, bit-identical bv.
__global__ __launch_bounds__(256, 2) void kF(const float* __restrict__ masks,
                                             const int* __restrict__ targets,
                                             unsigned* __restrict__ counts,
                                             unsigned* __restrict__ tsum,
                                             float* __restrict__ ce_sum,
                                             unsigned* __restrict__ n_valid,
                                             float* __restrict__ inter_ext) {
    // swizzle: addr(row, byte_in_row) = row*1024 + (byte_in_row ^ ((row&7)<<4))
    __shared__ __align__(16) short tileS[16 * 512];          // 16 KiB sigmoid tile
    __shared__ __align__(16) short oneh[48 * 512];           // 48 KiB one-hot B
    __shared__ float smem[160];   // ts_local[0..39], cred[64..67], vred[72..75]

    const int tid = threadIdx.x;
    const int l = tid & 63, w = tid >> 6;
    const int m = l & 15, quad = l >> 4;

    const int blk = blockIdx.x;
    const int b = blk >> 7;                 // 0..3
    const int seg = blk & 127;              // 0..127
    const int pxb = w * 128 + 2 * l;        // px within block [0,512)
    const int p0 = seg * 512 + pxb;         // px within image

    // targets FIRST (so the one-hot build's wait doesn't drain the prefetch)
    const int2 tg = *(const int2*)(targets + (size_t)b * HW + p0);
    const int tg0 = tg.x, tg1 = tg.y;

    const float* mp = masks + (size_t)b * Q * HW + p0;

    // ---- issue tile-0 prefetch (16 float2 in flight) ----
    float2 vv0[16], vv1[16];
    #pragma unroll
    for (int u = 0; u < 16; ++u)
        vv0[u] = *(const float2*)(mp + (size_t)u * HW);

    // ---- build one-hot B in LDS (once per block) ----
    unsigned* ts_local = (unsigned*)&smem[0];
    {
        int4 z = {0, 0, 0, 0};
        int4* o4 = (int4*)oneh;             // 48KB = 3072 int4 = 256 thr x 12
        #pragma unroll
        for (int i = 0; i < 12; ++i) o4[tid + i * 256] = z;
    }
    if (tid < C) ts_local[tid] = 0u;
    asm volatile("s_waitcnt lgkmcnt(0)" ::: "memory");
    __builtin_amdgcn_s_barrier();
    asm volatile("" ::: "memory");
    {
        const int r0 = (tg0 == 255) ? 40 : tg0;
        const int r1 = (tg1 == 255) ? 40 : tg1;
        *(short*)((char*)oneh + r0 * 1024 + ((2 * pxb) ^ ((r0 & 7) << 4))) =
            (short)0x3F80;
        *(short*)((char*)oneh + r1 * 1024 + ((2 * pxb + 2) ^ ((r1 & 7) << 4))) =
            (short)0x3F80;
    }
    asm volatile("s_waitcnt lgkmcnt(0)" ::: "memory");
    __builtin_amdgcn_s_barrier();
    asm volatile("" ::: "memory");

    // per-pixel softmax state (2 px/thread) — formulas/order == verified A-part
    float m20 = -INFINITY, m21 = -INFINITY;
    float s0 = 0.f, s1 = 0.f, xt0 = 0.f, xt1 = 0.f;
    int am0 = 0, am1 = 0;

    char* tb = (char*)tileS;
    char* ob = (char*)oneh;
    const int wbase = w * 256 + l * 4;      // my px-pair byte offset within a row
    const int colbase = w * 16;             // w0: cols 0-15, w1: 16-31, w2: 32-40
    const int brow = colbase + m;           // one-hot row (w2 m>8 -> zero rows)

    #pragma unroll
    for (int qt = 0; qt < 7; ++qt) {
        const int nu = (qt == 6) ? 4 : 16;

        // ---- issue NEXT tile's loads (fly during process+MFMA+barriers) ----
        if (qt < 6) {
            const int nn = (qt == 5) ? 4 : 16;
            const float* mq = mp + (size_t)((qt + 1) * 16) * HW;
            #pragma unroll
            for (int u = 0; u < 16; ++u)
                if (u < nn) vv1[u] = *(const float2*)(mq + (size_t)u * HW);
        }

        // ---- process current tile: softmax state + sigmoid->bf16 tile ----
        #pragma unroll
        for (int u = 0; u < 16; ++u)
            if (u < nu) {
                const int q = qt * 16 + u;
                const float v0 = vv0[u].x, v1 = vv0[u].y;
                s0 += __expf(v0);
                s1 += __expf(v1);
                am0 = (v0 > m20) ? q : am0;  m20 = fmaxf(m20, v0);
                am1 = (v1 > m21) ? q : am1;  m21 = fmaxf(m21, v1);
                xt0 = (q == tg0) ? v0 : xt0;
                xt1 = (q == tg1) ? v1 : xt1;
                const float g0 = __builtin_amdgcn_rcpf(1.f + __expf(-v0));
                const float g1 = __builtin_amdgcn_rcpf(1.f + __expf(-v1));
                const unsigned pk = (unsigned)(unsigned short)f2bf(g0) |
                                    ((unsigned)(unsigned short)f2bf(g1) << 16);
                *(unsigned*)(tb + ((u * 1024 + wbase) ^ ((u & 7) << 4))) = pk;
            }

        // publish tile: wait own ds ops only, raw barrier (prefetch stays live)
        asm volatile("s_waitcnt lgkmcnt(0)" ::: "memory");
        __builtin_amdgcn_s_barrier();
        asm volatile("" ::: "memory");

        // ---- MFMA phase: A from tile, B from prebuilt one-hot ----
        f32x4 acc = {0.f, 0.f, 0.f, 0.f};
        if (w < 3) {
            #pragma unroll
            for (int kc = 0; kc < 16; ++kc) {
                const short8 av = *(const short8*)(tb +
                    ((m * 1024 + kc * 64 + quad * 16) ^ ((m & 7) << 4)));
                const short8 bv = *(const short8*)(ob +
                    ((brow * 1024 + kc * 64 + quad * 16) ^ ((brow & 7) << 4)));
                acc = __builtin_amdgcn_mfma_f32_16x16x32_bf16(av, bv, acc, 0, 0, 0);
            }
        }
        asm volatile("s_waitcnt lgkmcnt(0)" ::: "memory");
        __builtin_amdgcn_s_barrier();
        asm volatile("" ::: "memory");

        // epilogue (regs only): D row = quad*4+reg, col = m
        if (w < 3 && !(w == 2 && m > 8)) {
            #pragma unroll
            for (int reg = 0; reg < 4; ++reg) {
                const int q = qt * 16 + quad * 4 + reg;
                if (q < 100)    // qt=6 rows 4..15 hold stale tile data: skipped
                    atomicAdd(&inter_ext[(size_t)(b * Q + q) * Cp1 + colbase + m],
                              acc[reg]);
            }
        }

        // rotate double-buffer (renamed away by full unroll)
        #pragma unroll
        for (int u = 0; u < 16; ++u) vv0[u] = vv1[u];
    }

    // ---- softmax epilogue (identical to verified A-part) ----
    float ce = 0.f;
    unsigned nv = 0u;
    if (tg0 != 255) {
        ce += __logf(s0) - xt0; nv++;
        atomicAdd(&counts[((size_t)b * Q + am0) * C + tg0], 1u);
        atomicAdd(&ts_local[tg0], 1u);
    }
    if (tg1 != 255) {
        ce += __logf(s1) - xt1; nv++;
        atomicAdd(&counts[((size_t)b * Q + am1) * C + tg1], 1u);
        atomicAdd(&ts_local[tg1], 1u);
    }
    for (int off = 32; off; off >>= 1) {
        ce += __shfl_xor(ce, off);
        nv += __shfl_xor(nv, off);
    }
    float* cred = &smem[64];
    unsigned* vred = (unsigned*)&smem[72];
    if (l == 0) { cred[w] = ce; vred[w] = nv; }
    __syncthreads();
    if (tid == 0) {
        atomicAdd(ce_sum, cred[0] + cred[1] + cred[2] + cred[3]);
        atomicAdd(n_valid, vred[0] + vred[1] + vred[2] + vred[3]);
    }
    if (tid < C) {
        unsigned t = ts_local[tid];
        if (t) atomicAdd(&tsum[b * C + tid], t);
    }
}

// Kernel C: finalize. src_sum derived from inter_ext's 41 columns. (Verified R11.)
__global__ __launch_bounds__(512) void kC(const float* __restrict__ logits,
                                          const unsigned* __restrict__ counts,
                                          const unsigned* __restrict__ tsum,
                                          const float* __restrict__ inter_ext,
                                          const float* __restrict__ ce_sum,
                                          const unsigned* __restrict__ n_valid,
                                          float* __restrict__ out) {
    int tid = threadIdx.x;
    __shared__ float dice_sum[C];
    __shared__ float ssum[B * Q];
    __shared__ float wred[8];
    __shared__ float s_lce;
    if (tid < C) dice_sum[tid] = 0.f;
    if (tid < B * Q) {                     // src_sum[bq] = sum of all 41 cols
        const float* r = inter_ext + (size_t)tid * Cp1;
        float t = 0.f;
        #pragma unroll
        for (int c = 0; c < Cp1; ++c) t += r[c];
        ssum[tid] = t;
    }

    float ce_acc = 0.f;
    for (int i = tid; i < B * Q; i += 512) {
        const unsigned* cnt = counts + (size_t)i * C;
        unsigned best = 0;
        int tc = C;
        #pragma unroll
        for (int c = 0; c < C; ++c) {
            unsigned v = cnt[c];
            if (v > best) { best = v; tc = c; }
        }
        if (tc != C) {
            const float* lg = logits + (size_t)i * Cp1;
            float mm = -INFINITY, xt = 0.f;
            #pragma unroll
            for (int c = 0; c < Cp1; ++c) {
                float v = lg[c];
                mm = fmaxf(mm, v);
                if (c == tc) xt = v;
            }
            float ss = 0.f;
            #pragma unroll
            for (int c = 0; c < Cp1; ++c) ss += __expf(lg[c] - mm);
            float nll = mm + __logf(ss) - xt;
            float p = __expf(-nll);
            float om = 1.f - p;
            ce_acc += om * om * nll;
        }
    }
    for (int off = 32; off; off >>= 1) ce_acc += __shfl_xor(ce_acc, off);
    if ((tid & 63) == 0) wred[tid >> 6] = ce_acc;
    __syncthreads();                        // also publishes ssum + dice_sum init
    if (tid == 0) {
        float t = 0.f;
        for (int w = 0; w < 8; ++w) t += wred[w];
        s_lce = t;
    }

    for (int i = tid; i < B * Q * C; i += 512) {
        int bq = i / C, c = i - bq * C;
        float denom = ssum[bq] + (float)tsum[(bq / Q) * C + c] + 1e-8f;
        atomicAdd(&dice_sum[c], 2.f * inter_ext[(size_t)bq * Cp1 + c] / denom);
    }
    __syncthreads();

    if (tid == 0) {
        float dl = 0.f;
        for (int c = 0; c < C; ++c) {
            unsigned ts = tsum[c] + tsum[C + c] + tsum[2 * C + c] + tsum[3 * C + c];
            if (ts > 0) dl += 1.f - dice_sum[c] * (1.f / (B * Q));
        }
        dl *= (1.f / C);
        float ce_mask = ce_sum[0] / fmaxf((float)n_valid[0], 1.f);
        float lce = s_lce * (1.f / (B * Q));
        out[0] = 2.f * lce + 5.f * ce_mask + 5.f * dl;
    }
}

extern "C" void kernel_launch(void* const* d_in, const int* in_sizes, int n_in,
                              void* d_out, int out_size, void* d_ws, size_t ws_size,
                              hipStream_t stream) {
    const float* logits  = (const float*)d_in[0];   // [B,Q,41] f32
    const float* masks   = (const float*)d_in[1];   // [B,Q,H,W] f32
    const int*   targets = (const int*)d_in[2];     // [B,H,W] int32
    float* out = (float*)d_out;                     // f32 scalar

    unsigned* ws        = (unsigned*)d_ws;
    unsigned* counts    = ws;                       // 16000 u32
    unsigned* tsum      = ws + 16000;               // 160 u32
    float*    ce_sum    = (float*)(ws + 16160);     // 1 f32
    unsigned* n_valid   = ws + 16161;               // 1 u32
    float*    inter_ext = (float*)(ws + 16162);     // 16400 f32

    kZ<<<64, 256, 0, stream>>>(ws, WS_WORDS);
    kF<<<FBLKS, 256, 0, stream>>>(masks, targets, counts, tsum, ce_sum, n_valid,
                                  inter_ext);
    kC<<<1, 512, 0, stream>>>(logits, counts, tsum, inter_ext, ce_sum, n_valid, out);
}